// Round 5
// baseline (309.475 us; speedup 1.0000x reference)
//
#include <hip/hip_runtime.h>
#include <hip/hip_cooperative_groups.h>

namespace cg = cooperative_groups;

#define BB 8
#define SS 4096
#define DD 768
#define EE 128
#define PP 8128   // E*(E-1)/2
#define MP 25
#define MT 3500
#define D4 192    // DD/4 float4 per row
#define NROWS_W  (BB*MT)   // 28000 words rows
#define NROWS_P  (BB*PP)   // 65024 pair rows (per head/tail)
#define NROWS_PR (BB*MP)   // 200 prompt rows
#define R_TOTAL  (NROWS_W + 2*NROWS_P + NROWS_PR)  // 158248
#define GBLK 1024
#define TBLK 256

typedef float f32x4 __attribute__((ext_vector_type(4)));

// output offsets (flat f32, reference return order)
#define OFF0 ((size_t)0)                        // prompts_embedding (8,25,768)
#define OFF1 (OFF0 + (size_t)BB*MP*DD)          // prompts_mask (8,25)
#define OFF2 (OFF1 + (size_t)BB*MP)             // words_embedding (8,3500,768)
#define OFF3 (OFF2 + (size_t)BB*MT*DD)          // word_mask (8,3500)
#define OFF4 (OFF3 + (size_t)BB*MT)             // pair_idx (8,8128,2)
#define OFF5 (OFF4 + (size_t)BB*PP*2)           // pair_mask (8,8128)
#define OFF6 (OFF5 + (size_t)BB*PP)             // head_rep (8,8128,768)
#define OFF7 (OFF6 + (size_t)BB*PP*DD)          // tail_rep (8,8128,768)

__device__ __forceinline__ int2 pair_rc(int p) {
    // r = max r with start(r) <= p, start(r) = r*(2E-1-r)/2
    int lo = 0, hi = EE - 2;
    while (lo < hi) {
        int mid = (lo + hi + 1) >> 1;
        int st = mid * (2 * EE - 1 - mid) / 2;
        if (st <= p) lo = mid; else hi = mid - 1;
    }
    int r = lo;
    int c = r + 1 + (p - r * (2 * EE - 1 - r) / 2);
    return make_int2(r, c);
}

// ---------------------------------------------------------------------------
// Prep: 24 blocks do index production + all scalar outputs.
//   role 0 (blk 0-7):   specials ballot-scan -> pos[], prompt mask (out1)
//   role 1 (blk 8-15):  word_mask (out3) + wordpos init + scatter
//   role 2 (blk 16-23): pair partition (coalesced strided chunks, 2-pass with
//                       LDS-cached ballot masks) -> pairrec, out4, out5
// ---------------------------------------------------------------------------
__device__ void do_prep(int blk, const int* __restrict__ ids,
                        const float* __restrict__ adj, const int* __restrict__ tlen,
                        const int* __restrict__ wm, float* __restrict__ out,
                        int* __restrict__ wordpos, int* __restrict__ pairrec,
                        int* __restrict__ pos)
{
    int role = blk >> 3, b = blk & 7;
    int t = threadIdx.x, wave = t >> 6, lane = t & 63;

    if (role == 0) {
        __shared__ int pos_s[32];
        __shared__ int spos[4 * 32];
        __shared__ int wcnt[4];
        __shared__ int woff[5];
        if (t < 32) pos_s[t] = -1;
        __syncthreads();
        const int* row = ids + b * SS;
        int base = 0;
        for (int c = 0; c < 16; ++c) {
            int p = wave * 1024 + c * 64 + lane;
            bool s = (row[p] == 1);
            unsigned long long m = __ballot(s);
            if (s) {
                int sl = base + __popcll(m & ((1ull << lane) - 1ull));
                if (sl < 32) spos[wave * 32 + sl] = p;
            }
            base += __popcll(m);
        }
        if (lane == 0) wcnt[wave] = base;
        __syncthreads();
        if (t == 0) {
            int acc = 0;
            for (int w = 0; w < 4; ++w) { woff[w] = acc; acc += wcnt[w]; }
            woff[4] = acc;
        }
        __syncthreads();
        {
            int cnt = wcnt[wave]; if (cnt > 32) cnt = 32;
            if (lane < cnt) {
                int g = woff[wave] + lane;
                if (g < MP) pos_s[g] = spos[wave * 32 + lane];
            }
        }
        __syncthreads();
        if (t < MP) {
            pos[b * MP + t] = pos_s[t];
            out[OFF1 + b * MP + t] = (t < woff[4]) ? 1.0f : 0.0f;
        }
    } else if (role == 1) {
        int L = tlen[b];
        for (int i = t; i < MT; i += TBLK) {
            out[OFF3 + b * MT + i] = (i < L) ? 1.0f : 0.0f;
            wordpos[b * MT + i] = -1;
        }
        __syncthreads();
        for (int i = t; i < SS; i += TBLK) {
            int v = wm[b * SS + i];
            if (v > 0 && v <= MT) wordpos[b * MT + v - 1] = i;
        }
    } else {
        __shared__ unsigned long long wmask[32][4];
        __shared__ int wsum[32][4];
        // pass 1: coalesced adj reads (lane-consecutive threads -> consecutive pairs)
        for (int ch = 0; ch < 32; ++ch) {
            int p = ch * TBLK + t;
            bool s = false;
            if (p < PP) {
                int2 rc = pair_rc(p);
                s = adj[((size_t)b * EE + rc.x) * EE + rc.y] > 0.5f;
            }
            unsigned long long m = __ballot(s);
            if (lane == 0) { wmask[ch][wave] = m; wsum[ch][wave] = __popcll(m); }
        }
        __syncthreads();
        int K = 0;
        for (int ch = 0; ch < 32; ++ch)
            K += wsum[ch][0] + wsum[ch][1] + wsum[ch][2] + wsum[ch][3];
        // pass 2: ranks from cached masks, write outputs
        int cbase = 0;
        for (int ch = 0; ch < 32; ++ch) {
            int p = ch * TBLK + t;
            if (p < PP) {
                unsigned long long m = wmask[ch][wave];
                bool s = (m >> lane) & 1ull;
                int woffw = 0;
                for (int w = 0; w < wave; ++w) woffw += wsum[ch][w];
                int rank = cbase + woffw + __popcll(m & ((1ull << lane) - 1ull));
                int q = s ? rank : (K + (p - rank));
                size_t oq = (size_t)b * PP + q;
                if (s) {
                    int2 rc = pair_rc(p);
                    pairrec[oq] = (int)(0x80000000u | ((unsigned)rc.x << 8) | (unsigned)rc.y);
                    out[OFF4 + oq * 2 + 0] = (float)rc.x;
                    out[OFF4 + oq * 2 + 1] = (float)rc.y;
                    out[OFF5 + oq] = 1.0f;
                } else {
                    pairrec[oq] = 0;
                    out[OFF4 + oq * 2 + 0] = -1.0f;
                    out[OFF4 + oq * 2 + 1] = -1.0f;
                    out[OFF5 + oq] = 0.0f;
                }
            }
            cbase += wsum[ch][0] + wsum[ch][1] + wsum[ch][2] + wsum[ch][3];
        }
    }
}

// ---------------------------------------------------------------------------
// Gather: pure row copier, one 768-f32 row per wave per iteration.
// ---------------------------------------------------------------------------
__device__ void do_gather(int blk, int nblk,
                          const float* __restrict__ te, const float* __restrict__ sr,
                          const int* __restrict__ wordpos, const int* __restrict__ pairrec,
                          const int* __restrict__ pos, float* __restrict__ out)
{
    int wave = threadIdx.x >> 6, lane = threadIdx.x & 63;
    int gw = blk * (TBLK / 64) + wave;
    int nw = nblk * (TBLK / 64);
    const f32x4* te4 = (const f32x4*)te;
    const f32x4* sr4 = (const f32x4*)sr;
    for (int row = gw; row < R_TOTAL; row += nw) {
        const f32x4* src4;
        f32x4* dst4;
        bool valid = true;
        bool stream_src = false;
        if (row < NROWS_W) {
            int b = row / MT;
            int s = wordpos[row];
            valid = (s >= 0);
            src4 = te4 + ((size_t)(b * SS + (valid ? s : 0))) * D4;
            dst4 = (f32x4*)(out + OFF2) + (size_t)row * D4;
            stream_src = true;
        } else if (row < NROWS_W + 2 * NROWS_P) {
            int idx2 = row - NROWS_W;
            bool head = idx2 < NROWS_P;
            int idx = head ? idx2 : idx2 - NROWS_P;
            int b = idx / PP;
            unsigned rec = (unsigned)pairrec[idx];
            int s = head ? ((rec >> 8) & 0x7F) : (rec & 0xFF);
            src4 = sr4 + ((size_t)(b * EE + s)) * D4;
            dst4 = (f32x4*)(out + (head ? OFF6 : OFF7)) + (size_t)idx * D4;
        } else {
            int j2 = row - (NROWS_W + 2 * NROWS_P);
            int b = j2 / MP;
            int s = pos[j2];
            valid = (s >= 0);
            src4 = te4 + ((size_t)(b * SS + (valid ? s : 0))) * D4;
            dst4 = (f32x4*)(out + OFF0) + (size_t)j2 * D4;
            stream_src = true;
        }
        #pragma unroll
        for (int k = 0; k < 3; ++k) {
            f32x4 v = (f32x4)(0.0f);
            if (valid) {
                v = stream_src ? __builtin_nontemporal_load(&src4[lane + 64 * k])
                               : src4[lane + 64 * k];
            }
            dst4[lane + 64 * k] = v;
        }
    }
}

// ---- cooperative fused kernel: prep (blocks 0-23) -> grid sync -> gather ----
__global__ __launch_bounds__(TBLK, 4) void k_coop(
    const float* __restrict__ te, const float* __restrict__ adj,
    const float* __restrict__ sr, const int* __restrict__ ids,
    const int* __restrict__ tlen, const int* __restrict__ wm,
    float* __restrict__ out, int* __restrict__ wordpos,
    int* __restrict__ pairrec, int* __restrict__ pos)
{
    int blk = blockIdx.x;
    if (blk < 24) do_prep(blk, ids, adj, tlen, wm, out, wordpos, pairrec, pos);
    __threadfence();
    cg::this_grid().sync();
    do_gather(blk, gridDim.x, te, sr, wordpos, pairrec, pos, out);
}

// ---- fallback pair (used only if cooperative launch is refused) ----
__global__ __launch_bounds__(TBLK) void k_prep_fb(
    const float* __restrict__ adj, const int* __restrict__ ids,
    const int* __restrict__ tlen, const int* __restrict__ wm,
    float* __restrict__ out, int* __restrict__ wordpos,
    int* __restrict__ pairrec, int* __restrict__ pos)
{
    do_prep(blockIdx.x, ids, adj, tlen, wm, out, wordpos, pairrec, pos);
}

__global__ __launch_bounds__(TBLK) void k_gather_fb(
    const float* __restrict__ te, const float* __restrict__ sr,
    const int* __restrict__ wordpos, const int* __restrict__ pairrec,
    const int* __restrict__ pos, float* __restrict__ out)
{
    do_gather(blockIdx.x, gridDim.x, te, sr, wordpos, pairrec, pos, out);
}

extern "C" void kernel_launch(void* const* d_in, const int* in_sizes, int n_in,
                              void* d_out, int out_size, void* d_ws, size_t ws_size,
                              hipStream_t stream) {
    const float* te   = (const float*)d_in[0];  // token_embeds (B,S,D)
    const float* adj  = (const float*)d_in[1];  // adj (B,E,E)
    const float* sr   = (const float*)d_in[2];  // span_rep (B,E,D)
    const int*   ids  = (const int*)d_in[3];    // input_ids (B,S)
    // d_in[4] attention_mask: unused
    const int*   tlen = (const int*)d_in[5];    // text_lengths (B,1)
    const int*   wm   = (const int*)d_in[6];    // words_mask (B,S)
    float* out = (float*)d_out;

    int* wordpos = (int*)d_ws;                   // B*MT
    int* pairrec = wordpos + BB * MT;            // B*PP
    int* pos     = pairrec + BB * PP;            // B*MP

    void* args[] = { (void*)&te, (void*)&adj, (void*)&sr, (void*)&ids,
                     (void*)&tlen, (void*)&wm, (void*)&out,
                     (void*)&wordpos, (void*)&pairrec, (void*)&pos };
    hipError_t err = hipLaunchCooperativeKernel((void*)k_coop, dim3(GBLK), dim3(TBLK),
                                                args, 0, stream);
    if (err != hipSuccess) {
        // deterministic fallback: identical work, two launches
        k_prep_fb<<<24, TBLK, 0, stream>>>(adj, ids, tlen, wm, out,
                                           wordpos, pairrec, pos);
        k_gather_fb<<<GBLK, TBLK, 0, stream>>>(te, sr, wordpos, pairrec, pos, out);
    }
}

// Round 6
// 156.761 us; speedup vs baseline: 1.9742x; 1.9742x over previous
//
#include <hip/hip_runtime.h>

#define BB 8
#define SS 4096
#define DD 768
#define EE 128
#define PP 8128   // E*(E-1)/2
#define MP 25
#define MT 3500
#define D4 192    // DD/4 float4 per row
#define NROWS_W  (BB*MT)   // 28000 words rows
#define NROWS_P  (BB*PP)   // 65024 pair rows (per head/tail)
#define NROWS_PR (BB*MP)   // 200 prompt rows
#define R_TOTAL  (NROWS_W + 2*NROWS_P + NROWS_PR)  // 158248

typedef float f32x4 __attribute__((ext_vector_type(4)));

// ---------------------------------------------------------------------------
// Kernel A: 24 blocks x 1024. role = blk>>3, b = blk&7. Index production only.
//   role 0: specials ballot-scan -> pos[b][25], nspec[b]
//   role 1: word_mask (out3) + wordpos init + scatter
//   role 2: pair stable-partition, coalesced 2-pass ballot -> pairrec
// ---------------------------------------------------------------------------
__global__ __launch_bounds__(1024) void k_prep(
    const int* __restrict__ ids, const float* __restrict__ adj,
    const int* __restrict__ wm, const int* __restrict__ tlen,
    float* __restrict__ out3,
    int* __restrict__ wordpos, int* __restrict__ pairrec,
    int* __restrict__ pos, int* __restrict__ nspec)
{
    int blk = blockIdx.x;
    int role = blk >> 3, b = blk & 7;
    int t = threadIdx.x, wave = t >> 6, lane = t & 63;

    if (role == 0) {
        // ---- specials scan: 16 waves x 256 tokens each ----
        __shared__ int pos_s[MP];
        __shared__ int spos[16 * 32];
        __shared__ int wcnt[16];
        __shared__ int woff[17];
        if (t < MP) pos_s[t] = -1;
        __syncthreads();
        const int* row = ids + b * SS;
        int base = 0;
        for (int c = 0; c < 4; ++c) {
            int p = wave * 256 + c * 64 + lane;
            bool s = (row[p] == 1);
            unsigned long long m = __ballot(s);
            if (s) {
                int sl = base + __popcll(m & ((1ull << lane) - 1ull));
                if (sl < 32) spos[wave * 32 + sl] = p;
            }
            base += __popcll(m);
        }
        if (lane == 0) wcnt[wave] = base;
        __syncthreads();
        if (t == 0) {
            int acc = 0;
            for (int w = 0; w < 16; ++w) { woff[w] = acc; acc += wcnt[w]; }
            woff[16] = acc;
        }
        __syncthreads();
        {
            int cnt = wcnt[wave]; if (cnt > 32) cnt = 32;
            if (lane < cnt) {
                int g = woff[wave] + lane;
                if (g < MP) pos_s[g] = spos[wave * 32 + lane];
            }
        }
        __syncthreads();
        if (t < MP) pos[b * MP + t] = pos_s[t];
        if (t == 0) nspec[b] = woff[16];
    } else if (role == 1) {
        // ---- word_mask + wordpos init, then scatter (same block => ordered) ----
        int L = tlen[b];
        for (int i = t; i < MT; i += 1024) {
            out3[b * MT + i] = (i < L) ? 1.0f : 0.0f;
            wordpos[b * MT + i] = -1;
        }
        __syncthreads();
        for (int i = t; i < SS; i += 1024) {
            int v = wm[b * SS + i];
            if (v > 0 && v <= MT) wordpos[b * MT + v - 1] = i;
        }
    } else {
        // ---- pair partition: coalesced 2-pass, ballot masks cached in LDS ----
        __shared__ unsigned long long wmask[8][16];
        __shared__ int wsum[8][16];
        // pass 1: p = ch*1024 + t -> consecutive threads read consecutive adj cells
        for (int ch = 0; ch < 8; ++ch) {
            int p = ch * 1024 + t;
            bool s = false;
            if (p < PP) {
                // r = max r with start(r) <= p, start(r) = r*(2E-1-r)/2
                int lo = 0, hi = EE - 2;
                while (lo < hi) {
                    int mid = (lo + hi + 1) >> 1;
                    int st = mid * (2 * EE - 1 - mid) / 2;
                    if (st <= p) lo = mid; else hi = mid - 1;
                }
                int r = lo;
                int c = r + 1 + (p - r * (2 * EE - 1 - r) / 2);
                s = adj[((size_t)b * EE + r) * EE + c] > 0.5f;
            }
            unsigned long long m = __ballot(s);
            if (lane == 0) { wmask[ch][wave] = m; wsum[ch][wave] = __popcll(m); }
        }
        __syncthreads();
        int K = 0;
        for (int ch = 0; ch < 8; ++ch)
            for (int w = 0; w < 16; ++w) K += wsum[ch][w];
        // pass 2: rank from cached masks, write packed record
        int cbase = 0;
        for (int ch = 0; ch < 8; ++ch) {
            int p = ch * 1024 + t;
            if (p < PP) {
                unsigned long long m = wmask[ch][wave];
                bool s = (m >> lane) & 1ull;
                int woffw = 0;
                for (int w = 0; w < wave; ++w) woffw += wsum[ch][w];
                int rank = cbase + woffw + __popcll(m & ((1ull << lane) - 1ull));
                int q = s ? rank : (K + (p - rank));
                int rec = 0;
                if (s) {
                    int lo = 0, hi = EE - 2;
                    while (lo < hi) {
                        int mid = (lo + hi + 1) >> 1;
                        int st = mid * (2 * EE - 1 - mid) / 2;
                        if (st <= p) lo = mid; else hi = mid - 1;
                    }
                    int r = lo;
                    int c = r + 1 + (p - r * (2 * EE - 1 - r) / 2);
                    rec = (int)(0x80000000u | ((unsigned)r << 8) | (unsigned)c);
                }
                pairrec[(size_t)b * PP + q] = rec;
            }
            for (int w = 0; w < 16; ++w) cbase += wsum[ch][w];
        }
    }
}

// ---------------------------------------------------------------------------
// Kernel B (unchanged from the 150 us run): unified gather, one 768-f32 row
// per wave per iteration. Row space: [0,28000) words | [28000,93024) head |
// [93024,158048) tail | [158048,158248) prompts. Lane 0 of head rows writes
// pair_idx/pair_mask; lane 0 of prompt rows writes prompt mask.
// ---------------------------------------------------------------------------
__global__ __launch_bounds__(256) void k_gather(
    const float* __restrict__ te, const float* __restrict__ sr,
    const int* __restrict__ wordpos, const int* __restrict__ pairrec,
    const int* __restrict__ pos, const int* __restrict__ nspec,
    float* __restrict__ out0, float* __restrict__ out1, float* __restrict__ out2,
    float* __restrict__ out4, float* __restrict__ out5,
    float* __restrict__ out6, float* __restrict__ out7)
{
    int gw = blockIdx.x * 4 + (threadIdx.x >> 6);
    int lane = threadIdx.x & 63;
    int nw = gridDim.x * 4;
    const f32x4* te4 = (const f32x4*)te;
    const f32x4* sr4 = (const f32x4*)sr;
    for (int row = gw; row < R_TOTAL; row += nw) {
        const f32x4* src4;
        f32x4* dst4;
        bool valid = true;
        bool stream_src = false;
        if (row < NROWS_W) {
            int b = row / MT;
            int s = wordpos[row];
            valid = (s >= 0);
            src4 = te4 + ((size_t)(b * SS + (valid ? s : 0))) * D4;
            dst4 = (f32x4*)out2 + (size_t)row * D4;
            stream_src = true;
        } else if (row < NROWS_W + 2 * NROWS_P) {
            int idx2 = row - NROWS_W;
            bool head = idx2 < NROWS_P;
            int idx = head ? idx2 : idx2 - NROWS_P;
            int b = idx / PP;
            unsigned rec = (unsigned)pairrec[idx];
            int r = (rec >> 8) & 0x7F;
            int c = rec & 0xFF;
            int s = head ? r : c;      // rec==0 (unselected) -> row 0, matches ref
            src4 = sr4 + ((size_t)(b * EE + s)) * D4;
            dst4 = (f32x4*)(head ? out6 : out7) + (size_t)idx * D4;
            if (head && lane == 0) {
                bool sel = rec != 0u;
                out4[(size_t)idx * 2 + 0] = sel ? (float)r : -1.0f;
                out4[(size_t)idx * 2 + 1] = sel ? (float)c : -1.0f;
                out5[idx] = sel ? 1.0f : 0.0f;
            }
        } else {
            int j2 = row - (NROWS_W + 2 * NROWS_P);
            int b = j2 / MP;
            int j = j2 - b * MP;
            int s = pos[j2];
            valid = (s >= 0);
            src4 = te4 + ((size_t)(b * SS + (valid ? s : 0))) * D4;
            dst4 = (f32x4*)out0 + (size_t)j2 * D4;
            stream_src = true;
            if (lane == 0) out1[j2] = (j < nspec[b]) ? 1.0f : 0.0f;
        }
        #pragma unroll
        for (int k = 0; k < 3; ++k) {
            f32x4 v = (f32x4)(0.0f);
            if (valid) {
                v = stream_src ? __builtin_nontemporal_load(&src4[lane + 64 * k])
                               : src4[lane + 64 * k];
            }
            dst4[lane + 64 * k] = v;   // plain store
        }
    }
}

extern "C" void kernel_launch(void* const* d_in, const int* in_sizes, int n_in,
                              void* d_out, int out_size, void* d_ws, size_t ws_size,
                              hipStream_t stream) {
    const float* te   = (const float*)d_in[0];  // token_embeds (B,S,D)
    const float* adj  = (const float*)d_in[1];  // adj (B,E,E)
    const float* sr   = (const float*)d_in[2];  // span_rep (B,E,D)
    const int*   ids  = (const int*)d_in[3];    // input_ids (B,S)
    // d_in[4] attention_mask: unused
    const int*   tlen = (const int*)d_in[5];    // text_lengths (B,1)
    const int*   wm   = (const int*)d_in[6];    // words_mask (B,S)
    float* out = (float*)d_out;

    size_t off0 = 0;
    size_t off1 = off0 + (size_t)BB * MP * DD;   // prompts_embedding
    size_t off2 = off1 + (size_t)BB * MP;        // prompts_mask
    size_t off3 = off2 + (size_t)BB * MT * DD;   // words_embedding
    size_t off4 = off3 + (size_t)BB * MT;        // word_mask
    size_t off5 = off4 + (size_t)BB * PP * 2;    // pair_idx
    size_t off6 = off5 + (size_t)BB * PP;        // pair_mask
    size_t off7 = off6 + (size_t)BB * PP * DD;   // head_rep -> tail_rep

    int* wordpos = (int*)d_ws;                   // B*MT
    int* pairrec = wordpos + BB * MT;            // B*PP
    int* pos     = pairrec + BB * PP;            // B*MP
    int* nspec   = pos + BB * MP;                // B

    k_prep<<<24, 1024, 0, stream>>>(ids, adj, wm, tlen, out + off3,
                                    wordpos, pairrec, pos, nspec);
    k_gather<<<2048, 256, 0, stream>>>(te, sr, wordpos, pairrec, pos, nspec,
                                       out + off0, out + off1, out + off2,
                                       out + off4, out + off5,
                                       out + off6, out + off7);
}

// Round 7
// 153.268 us; speedup vs baseline: 2.0192x; 1.0228x over previous
//
#include <hip/hip_runtime.h>

#define BB 8
#define SS 4096
#define DD 768
#define EE 128
#define PP 8128   // E*(E-1)/2
#define MP 25
#define MT 3500
#define D4 192    // DD/4 float4 per row
#define NROWS_W  (BB*MT)   // 28000 words rows
#define NROWS_P  (BB*PP)   // 65024 pair rows (per head/tail)
#define NROWS_PR (BB*MP)   // 200 prompt rows
#define R_TOTAL  (NROWS_W + 2*NROWS_P + NROWS_PR)  // 158248

typedef float f32x4 __attribute__((ext_vector_type(4)));

// ---------------------------------------------------------------------------
// Kernel A: 24 blocks x 1024. role = blk>>3, b = blk&7. Index production only.
//   role 0: specials ballot-scan -> pos[b][25], nspec[b]
//   role 1: word_mask (out3) + wordpos init + scatter
//   role 2: pair stable-partition, coalesced 2-pass ballot -> pairrec
// ---------------------------------------------------------------------------
__global__ __launch_bounds__(1024) void k_prep(
    const int* __restrict__ ids, const float* __restrict__ adj,
    const int* __restrict__ wm, const int* __restrict__ tlen,
    float* __restrict__ out3,
    int* __restrict__ wordpos, int* __restrict__ pairrec,
    int* __restrict__ pos, int* __restrict__ nspec)
{
    int blk = blockIdx.x;
    int role = blk >> 3, b = blk & 7;
    int t = threadIdx.x, wave = t >> 6, lane = t & 63;

    if (role == 0) {
        __shared__ int pos_s[MP];
        __shared__ int spos[16 * 32];
        __shared__ int wcnt[16];
        __shared__ int woff[17];
        if (t < MP) pos_s[t] = -1;
        __syncthreads();
        const int* row = ids + b * SS;
        int base = 0;
        for (int c = 0; c < 4; ++c) {
            int p = wave * 256 + c * 64 + lane;
            bool s = (row[p] == 1);
            unsigned long long m = __ballot(s);
            if (s) {
                int sl = base + __popcll(m & ((1ull << lane) - 1ull));
                if (sl < 32) spos[wave * 32 + sl] = p;
            }
            base += __popcll(m);
        }
        if (lane == 0) wcnt[wave] = base;
        __syncthreads();
        if (t == 0) {
            int acc = 0;
            for (int w = 0; w < 16; ++w) { woff[w] = acc; acc += wcnt[w]; }
            woff[16] = acc;
        }
        __syncthreads();
        {
            int cnt = wcnt[wave]; if (cnt > 32) cnt = 32;
            if (lane < cnt) {
                int g = woff[wave] + lane;
                if (g < MP) pos_s[g] = spos[wave * 32 + lane];
            }
        }
        __syncthreads();
        if (t < MP) pos[b * MP + t] = pos_s[t];
        if (t == 0) nspec[b] = woff[16];
    } else if (role == 1) {
        int L = tlen[b];
        for (int i = t; i < MT; i += 1024) {
            out3[b * MT + i] = (i < L) ? 1.0f : 0.0f;
            wordpos[b * MT + i] = -1;
        }
        __syncthreads();
        for (int i = t; i < SS; i += 1024) {
            int v = wm[b * SS + i];
            if (v > 0 && v <= MT) wordpos[b * MT + v - 1] = i;
        }
    } else {
        __shared__ unsigned long long wmask[8][16];
        __shared__ int wsum[8][16];
        for (int ch = 0; ch < 8; ++ch) {
            int p = ch * 1024 + t;
            bool s = false;
            if (p < PP) {
                int lo = 0, hi = EE - 2;
                while (lo < hi) {
                    int mid = (lo + hi + 1) >> 1;
                    int st = mid * (2 * EE - 1 - mid) / 2;
                    if (st <= p) lo = mid; else hi = mid - 1;
                }
                int r = lo;
                int c = r + 1 + (p - r * (2 * EE - 1 - r) / 2);
                s = adj[((size_t)b * EE + r) * EE + c] > 0.5f;
            }
            unsigned long long m = __ballot(s);
            if (lane == 0) { wmask[ch][wave] = m; wsum[ch][wave] = __popcll(m); }
        }
        __syncthreads();
        int K = 0;
        for (int ch = 0; ch < 8; ++ch)
            for (int w = 0; w < 16; ++w) K += wsum[ch][w];
        int cbase = 0;
        for (int ch = 0; ch < 8; ++ch) {
            int p = ch * 1024 + t;
            if (p < PP) {
                unsigned long long m = wmask[ch][wave];
                bool s = (m >> lane) & 1ull;
                int woffw = 0;
                for (int w = 0; w < wave; ++w) woffw += wsum[ch][w];
                int rank = cbase + woffw + __popcll(m & ((1ull << lane) - 1ull));
                int q = s ? rank : (K + (p - rank));
                int rec = 0;
                if (s) {
                    int lo = 0, hi = EE - 2;
                    while (lo < hi) {
                        int mid = (lo + hi + 1) >> 1;
                        int st = mid * (2 * EE - 1 - mid) / 2;
                        if (st <= p) lo = mid; else hi = mid - 1;
                    }
                    int r = lo;
                    int c = r + 1 + (p - r * (2 * EE - 1 - r) / 2);
                    rec = (int)(0x80000000u | ((unsigned)r << 8) | (unsigned)c);
                }
                pairrec[(size_t)b * PP + q] = rec;
            }
            for (int w = 0; w < 16; ++w) cbase += wsum[ch][w];
        }
    }
}

// ---------------------------------------------------------------------------
// Row address setup for the unified gather row space:
// [0,28000) words | [28000,93024) head | [93024,158048) tail | +200 prompts.
// Side-effect: lane0 scalar outputs (pair_idx/pair_mask, prompt mask).
// ---------------------------------------------------------------------------
__device__ __forceinline__ void row_setup(
    int row, int lane,
    const f32x4* __restrict__ te4, const f32x4* __restrict__ sr4,
    const int* __restrict__ wordpos, const int* __restrict__ pairrec,
    const int* __restrict__ pos, const int* __restrict__ nspec,
    float* __restrict__ out1, float* __restrict__ out4, float* __restrict__ out5,
    f32x4* __restrict__ o0, f32x4* __restrict__ o2,
    f32x4* __restrict__ o6, f32x4* __restrict__ o7,
    const f32x4** src, f32x4** dst, bool* valid)
{
    if (row < NROWS_W) {
        int b = row / MT;
        int s = wordpos[row];
        *valid = (s >= 0);
        *src = te4 + ((size_t)(b * SS + (s >= 0 ? s : 0))) * D4;
        *dst = o2 + (size_t)row * D4;
    } else if (row < NROWS_W + 2 * NROWS_P) {
        int idx2 = row - NROWS_W;
        bool head = idx2 < NROWS_P;
        int idx = head ? idx2 : idx2 - NROWS_P;
        int b = idx / PP;
        unsigned rec = (unsigned)pairrec[idx];
        int r = (rec >> 8) & 0x7F;
        int c = rec & 0xFF;
        int s = head ? r : c;      // rec==0 (unselected) -> row 0, matches ref
        *valid = true;
        *src = sr4 + ((size_t)(b * EE + s)) * D4;
        *dst = (head ? o6 : o7) + (size_t)idx * D4;
        if (head && lane == 0) {
            bool sel = rec != 0u;
            out4[(size_t)idx * 2 + 0] = sel ? (float)r : -1.0f;
            out4[(size_t)idx * 2 + 1] = sel ? (float)c : -1.0f;
            out5[idx] = sel ? 1.0f : 0.0f;
        }
    } else {
        int j2 = row - (NROWS_W + 2 * NROWS_P);
        int b = j2 / MP;
        int j = j2 - b * MP;
        int s = pos[j2];
        *valid = (s >= 0);
        *src = te4 + ((size_t)(b * SS + (s >= 0 ? s : 0))) * D4;
        *dst = o0 + (size_t)j2 * D4;
        if (lane == 0) out1[j2] = (j < nspec[b]) ? 1.0f : 0.0f;
    }
}

// ---------------------------------------------------------------------------
// Kernel B: unified gather, 2-row software pipeline per wave iteration.
// Both rows' index loads + 6 source float4 loads issue before any store.
// ---------------------------------------------------------------------------
__global__ __launch_bounds__(256) void k_gather(
    const float* __restrict__ te, const float* __restrict__ sr,
    const int* __restrict__ wordpos, const int* __restrict__ pairrec,
    const int* __restrict__ pos, const int* __restrict__ nspec,
    float* __restrict__ out0, float* __restrict__ out1, float* __restrict__ out2,
    float* __restrict__ out4, float* __restrict__ out5,
    float* __restrict__ out6, float* __restrict__ out7)
{
    int gw = blockIdx.x * 4 + (threadIdx.x >> 6);
    int lane = threadIdx.x & 63;
    int nw = gridDim.x * 4;
    const f32x4* te4 = (const f32x4*)te;
    const f32x4* sr4 = (const f32x4*)sr;
    f32x4* o0 = (f32x4*)out0;
    f32x4* o2 = (f32x4*)out2;
    f32x4* o6 = (f32x4*)out6;
    f32x4* o7 = (f32x4*)out7;

    for (int row = gw; row < R_TOTAL; row += 2 * nw) {
        int rowB = row + nw;
        bool hasB = rowB < R_TOTAL;

        const f32x4 *sA, *sB = nullptr;
        f32x4 *dA, *dB = nullptr;
        bool vA, vB = false;
        row_setup(row, lane, te4, sr4, wordpos, pairrec, pos, nspec,
                  out1, out4, out5, o0, o2, o6, o7, &sA, &dA, &vA);
        f32x4 a0 = (f32x4)(0.0f), a1 = (f32x4)(0.0f), a2 = (f32x4)(0.0f);
        if (vA) { a0 = sA[lane]; a1 = sA[lane + 64]; a2 = sA[lane + 128]; }

        f32x4 b0 = (f32x4)(0.0f), b1 = (f32x4)(0.0f), b2 = (f32x4)(0.0f);
        if (hasB) {
            row_setup(rowB, lane, te4, sr4, wordpos, pairrec, pos, nspec,
                      out1, out4, out5, o0, o2, o6, o7, &sB, &dB, &vB);
            if (vB) { b0 = sB[lane]; b1 = sB[lane + 64]; b2 = sB[lane + 128]; }
        }

        dA[lane] = a0; dA[lane + 64] = a1; dA[lane + 128] = a2;
        if (hasB) {
            dB[lane] = b0; dB[lane + 64] = b1; dB[lane + 128] = b2;
        }
    }
}

extern "C" void kernel_launch(void* const* d_in, const int* in_sizes, int n_in,
                              void* d_out, int out_size, void* d_ws, size_t ws_size,
                              hipStream_t stream) {
    const float* te   = (const float*)d_in[0];  // token_embeds (B,S,D)
    const float* adj  = (const float*)d_in[1];  // adj (B,E,E)
    const float* sr   = (const float*)d_in[2];  // span_rep (B,E,D)
    const int*   ids  = (const int*)d_in[3];    // input_ids (B,S)
    // d_in[4] attention_mask: unused
    const int*   tlen = (const int*)d_in[5];    // text_lengths (B,1)
    const int*   wm   = (const int*)d_in[6];    // words_mask (B,S)
    float* out = (float*)d_out;

    size_t off0 = 0;
    size_t off1 = off0 + (size_t)BB * MP * DD;   // prompts_embedding
    size_t off2 = off1 + (size_t)BB * MP;        // prompts_mask
    size_t off3 = off2 + (size_t)BB * MT * DD;   // words_embedding
    size_t off4 = off3 + (size_t)BB * MT;        // word_mask
    size_t off5 = off4 + (size_t)BB * PP * 2;    // pair_idx
    size_t off6 = off5 + (size_t)BB * PP;        // pair_mask
    size_t off7 = off6 + (size_t)BB * PP * DD;   // head_rep -> tail_rep

    int* wordpos = (int*)d_ws;                   // B*MT
    int* pairrec = wordpos + BB * MT;            // B*PP
    int* pos     = pairrec + BB * PP;            // B*MP
    int* nspec   = pos + BB * MP;                // B

    k_prep<<<24, 1024, 0, stream>>>(ids, adj, wm, tlen, out + off3,
                                    wordpos, pairrec, pos, nspec);
    k_gather<<<2048, 256, 0, stream>>>(te, sr, wordpos, pairrec, pos, nspec,
                                       out + off0, out + off1, out + off2,
                                       out + off4, out + off5,
                                       out + off6, out + off7);
}